// Round 4
// baseline (182.276 us; speedup 1.0000x reference)
//
#include <hip/hip_runtime.h>

typedef __bf16 bf16x8 __attribute__((ext_vector_type(8)));
typedef float f32x4 __attribute__((ext_vector_type(4)));
typedef unsigned int u32x4 __attribute__((ext_vector_type(4)));

// Pack hi16(lo), hi16(hi) -> one u32 holding bf16 pair [lo, hi] (truncation;
// error budget analysis: threshold 2478 vs expected O(10-50) error).
__device__ __forceinline__ unsigned int pkhi(float lo, float hi) {
  return __builtin_amdgcn_perm(__float_as_uint(hi), __float_as_uint(lo), 0x07060302u);
}
__device__ __forceinline__ bf16x8 cvt8(float4 a, float4 b) {
  u32x4 v;
  v.x = pkhi(a.x, a.y); v.y = pkhi(a.z, a.w);
  v.z = pkhi(b.x, b.y); v.w = pkhi(b.z, b.w);
  return __builtin_bit_cast(bf16x8, v);
}

// ---------------------------------------------------------------------------
// t2i pooled score, fp32 inputs converted in-register (no staging). Two
// images per block vs one 16-caption group. Verified D mapping (R1/R3):
// col = lane&15 (B row), row = (lane>>4)*4 + reg (object).
// ---------------------------------------------------------------------------
template<int MT, int W, int O>
__device__ __forceinline__ void t2i_direct(
    const float* __restrict__ A,    // [128, O, 128] fp32
    const float* __restrict__ B,    // [128, W, 128] fp32 (flat rows c*W+w)
    const int* __restrict__ obj_l, const int* __restrict__ cap_l,
    float* __restrict__ pooled,     // [128,128] fp32
    int vb, float* wmax)            // wmax LDS >= 2*16*W floats
{
  const int i0  = (vb >> 3) * 2;
  const int cg0 = (vb & 7) * 16;
  const int tid = threadIdx.x;
  const int wv = tid >> 6, lane = tid & 63;
  const int quad = lane >> 4, n16 = lane & 15;
  const int ol0 = obj_l[i0], ol1 = obj_l[i0 + 1];

  // A fragments in registers: af[im][t][s] = A[row=t*16+n16][k=s*32+quad*8..+7]
  bf16x8 af[2][MT][4];
#pragma unroll
  for (int imi = 0; imi < 2; ++imi)
#pragma unroll
    for (int t = 0; t < MT; ++t) {
      const int o = t * 16 + n16;
#pragma unroll
      for (int s = 0; s < 4; ++s) {
        if (o < O) {                       // predicated: never read OOB rows
          const float* ap = A + ((size_t)(i0 + imi) * O + o) * 128 + s * 32 + quad * 8;
          float4 a0 = *(const float4*)ap;
          float4 a1 = *(const float4*)(ap + 4);
          af[imi][t][s] = cvt8(a0, a1);
        } else {
          u32x4 z = {0u, 0u, 0u, 0u};
          af[imi][t][s] = __builtin_bit_cast(bf16x8, z);
        }
      }
    }

  // B tiles: flat row r = cg0*W + nt*16 + n16, k = s*32 + quad*8
  const float* Bbase = B + ((size_t)cg0 * W + n16) * 128 + quad * 8;

  for (int nt = wv; nt < W; nt += 4) {     // 16*W rows / 16 = W tiles, exact
    const float* bp = Bbase + (size_t)(nt * 16) * 128;
    bf16x8 bfrag[4];
#pragma unroll
    for (int s = 0; s < 4; ++s) {
      float4 b0 = *(const float4*)(bp + s * 32);
      float4 b1 = *(const float4*)(bp + s * 32 + 4);
      bfrag[s] = cvt8(b0, b1);
    }

    f32x4 acc[2][MT];
#pragma unroll
    for (int imi = 0; imi < 2; ++imi)
#pragma unroll
      for (int t = 0; t < MT; ++t) { f32x4 z = {0.f,0.f,0.f,0.f}; acc[imi][t] = z; }
#pragma unroll
    for (int s = 0; s < 4; ++s)
#pragma unroll
      for (int imi = 0; imi < 2; ++imi)
#pragma unroll
        for (int t = 0; t < MT; ++t)
          acc[imi][t] = __builtin_amdgcn_mfma_f32_16x16x32_bf16(
              af[imi][t][s], bfrag[s], acc[imi][t], 0, 0, 0);

#pragma unroll
    for (int imi = 0; imi < 2; ++imi) {
      const int ol = imi ? ol1 : ol0;
      float m = -3.0e38f;
#pragma unroll
      for (int t = 0; t < MT; ++t)
#pragma unroll
        for (int r = 0; r < 4; ++r) {
          int o = t * 16 + quad * 4 + r;
          if (o < ol) m = fmaxf(m, acc[imi][t][r]);
        }
      m = fmaxf(m, __shfl_xor(m, 16));
      m = fmaxf(m, __shfl_xor(m, 32));
      if (quad == 0) wmax[imi * (16 * W) + nt * 16 + n16] = m;
    }
  }
  __syncthreads();

  if (tid < 32) {
    const int imi = tid >> 4, c = tid & 15;
    const float* wp = wmax + imi * (16 * W) + c * W;
    float ssum = 0.f;
    for (int w = 0; w < W; ++w) ssum += wp[w];
    const int cc = cg0 + c;
    pooled[((i0 + imi) << 7) + cc] = ssum / (float)cap_l[cc];
  }
}

// ---------------------------------------------------------------------------
// Inline hinge loss, 256 threads (run by the LAST block to finish).
// Coalesced: thread (half, j) scans 64 rows with j contiguous. Row max via
// wave shfl (64 consecutive j per wave) + LDS atomicMax on float bits
// (hinges >= 0 so int compare == float compare). Col max in registers.
// ---------------------------------------------------------------------------
__device__ __forceinline__ void loss_inline(
    const float* __restrict__ p1, const float* __restrict__ p2,
    float* __restrict__ out, float* smem)
{
  float* diag    = smem;            // [128]
  int*   rowmaxi = (int*)(smem + 128);  // [128]
  float* colmax  = smem + 256;      // [2][128]
  float* wred    = smem + 512;      // [4]
  const int tid = threadIdx.x;
  const int j = tid & 127, half = tid >> 7;
  if (half == 0) {
    diag[j] = p1[j * 129] + p2[j * 129];
    rowmaxi[j] = 0;                 // float bits of 0.0f
  }
  __syncthreads();

  float colp = 0.f;
  for (int rr = 0; rr < 64; ++rr) {
    const int row = half * 64 + rr;
    const float sc = p1[row * 128 + j] + p2[row * 128 + j];
    float rh = (j == row) ? 0.f : fmaxf(0.2f + sc - diag[row], 0.f);
    const float ch = (j == row) ? 0.f : fmaxf(0.2f + sc - diag[j], 0.f);
    colp = fmaxf(colp, ch);
#pragma unroll
    for (int o = 32; o; o >>= 1) rh = fmaxf(rh, __shfl_xor(rh, o));
    if ((tid & 63) == 0) atomicMax(&rowmaxi[row], __float_as_int(rh));
  }
  colmax[half * 128 + j] = colp;
  __syncthreads();

  float v;
  if (tid < 128) v = __int_as_float(rowmaxi[tid]);
  else           v = fmaxf(colmax[tid - 128], colmax[128 + (tid - 128)]);
#pragma unroll
  for (int o = 32; o; o >>= 1) v += __shfl_xor(v, o);
  if ((tid & 63) == 0) wred[tid >> 6] = v;
  __syncthreads();
  if (tid == 0) out[0] = wred[0] + wred[1] + wred[2] + wred[3];
}

// ---------------------------------------------------------------------------
// One kernel: blocks [0,512) term1, [512,1024) term2; last block to finish
// runs the loss (decoupled-completion: release fence + device-scope counter).
// ---------------------------------------------------------------------------
__global__ __launch_bounds__(256) void fused_kernel(
    const float* __restrict__ im, const float* __restrict__ s32,
    const float* __restrict__ pred, const float* __restrict__ crp,
    const int* __restrict__ im_l, const int* __restrict__ s_l,
    const int* __restrict__ pred_l, const int* __restrict__ crl,
    float* __restrict__ p1, float* __restrict__ p2,
    unsigned int* __restrict__ counter, float* __restrict__ out)
{
  __shared__ float smem[1600];
  __shared__ int lastFlag;
  const int b = blockIdx.x;

  if (b < 512) t2i_direct<3, 50, 36>(im,   s32, im_l,   s_l, p1, b,       smem);
  else         t2i_direct<2, 30, 25>(pred, crp, pred_l, crl, p2, b - 512, smem);

  __syncthreads();                  // all pooled stores drained (vmcnt(0))
  if (threadIdx.x == 0) {
    __threadfence();                // agent-scope release: L2 writeback
    lastFlag = (atomicAdd(counter, 1u) == 1023u) ? 1 : 0;
  }
  __syncthreads();
  if (lastFlag) {
    __threadfence();                // acquire: invalidate stale L1/L2
    loss_inline(p1, p2, out, smem);
  }
}

// ---------------------------------------------------------------------------
extern "C" void kernel_launch(void* const* d_in, const int* in_sizes, int n_in,
                              void* d_out, int out_size, void* d_ws, size_t ws_size,
                              hipStream_t stream)
{
  const float* im     = (const float*)d_in[0];
  const int*   im_l   = (const int*)  d_in[1];
  const float* s32    = (const float*)d_in[2];
  const int*   s_l    = (const int*)  d_in[3];
  const float* pred   = (const float*)d_in[4];
  const int*   pred_l = (const int*)  d_in[5];
  // d_in[6], d_in[7] unused by the reference.
  const float* crp    = (const float*)d_in[8];
  const int*   crl    = (const int*)  d_in[9];

  char* ws = (char*)d_ws;
  float* p1 = (float*)ws;                                   // 64 KB
  float* p2 = (float*)(ws + 128 * 128 * 4);                 // 64 KB
  unsigned int* counter = (unsigned int*)(ws + 2 * 128 * 128 * 4);

  hipMemsetAsync((void*)counter, 0, sizeof(unsigned int), stream);
  hipLaunchKernelGGL(fused_kernel, dim3(1024), dim3(256), 0, stream,
                     im, s32, pred, crp, im_l, s_l, pred_l, crl,
                     p1, p2, counter, (float*)d_out);
}

// Round 5
// 157.765 us; speedup vs baseline: 1.1554x; 1.1554x over previous
//
#include <hip/hip_runtime.h>

typedef __bf16 bf16x8 __attribute__((ext_vector_type(8)));
typedef float f32x4 __attribute__((ext_vector_type(4)));
typedef unsigned int u32x4 __attribute__((ext_vector_type(4)));

__device__ __forceinline__ unsigned short f2bf(float f) {
  unsigned int u = __float_as_uint(f);
  u += 0x7FFFu + ((u >> 16) & 1u);   // round-to-nearest-even
  return (unsigned short)(u >> 16);
}

__device__ __forceinline__ bf16x8 load_frag(const unsigned short* p) {
  u32x4 v = *(const u32x4*)p;
  return __builtin_bit_cast(bf16x8, v);
}

// ---------------------------------------------------------------------------
// Convert all four used fp32 tensors to bf16 (object dims zero-padded to a
// multiple of 16 for MFMA M-tiling). Verified R1/R3 (absmax 0.0).
// Also zeroes the completion counter for the fused kernel (stream-ordered).
// ---------------------------------------------------------------------------
__global__ __launch_bounds__(256) void convert_all(
    const float* __restrict__ im, const float* __restrict__ s,
    const float* __restrict__ pred, const float* __restrict__ crp,
    unsigned short* __restrict__ imb, unsigned short* __restrict__ sb,
    unsigned short* __restrict__ pb, unsigned short* __restrict__ cb,
    unsigned int* __restrict__ counter)
{
  int b = blockIdx.x;
  if (b == 0 && threadIdx.x == 0) *counter = 0u;   // ws is 0xAA-poisoned
  const float* src; unsigned short* dst; int O, OP, base;
  if (b < 768)       { src = im;   dst = imb; O = 36; OP = 48; base = 0; }
  else if (b < 1568) { src = s;    dst = sb;  O = 50; OP = 50; base = 768; }
  else if (b < 2080) { src = pred; dst = pb;  O = 25; OP = 32; base = 1568; }
  else               { src = crp;  dst = cb;  O = 30; OP = 30; base = 2080; }
  int tid = (b - base) * 256 + (int)threadIdx.x;          // one thread = 4 floats
  int total = 128 * OP * 32;
  if (tid >= total) return;
  int d4 = tid & 31;
  int o  = (tid >> 5) % OP;
  int bb = tid / (OP * 32);
  unsigned short r0 = 0, r1 = 0, r2 = 0, r3 = 0;
  if (o < O) {
    const float4 v = *(const float4*)(src + ((bb * O + o) << 7) + (d4 << 2));
    r0 = f2bf(v.x); r1 = f2bf(v.y); r2 = f2bf(v.z); r3 = f2bf(v.w);
  }
  ushort4 outv; outv.x = r0; outv.y = r1; outv.z = r2; outv.w = r3;
  *(ushort4*)(dst + (size_t)tid * 4) = outv;
}

// ---------------------------------------------------------------------------
// t2i pooled score, TWO images per block vs one 16-caption group (R3-proven).
// D mapping (verified): col = lane&15 (B row), row = (lane>>4)*4+reg (object).
// ---------------------------------------------------------------------------
template<int MT, int W>
__device__ __forceinline__ void t2i_im2(
    const unsigned short* __restrict__ A,    // [128, MT*16, 128] bf16
    const unsigned short* __restrict__ Bw,   // [128, W, 128] bf16
    const int* __restrict__ obj_l, const int* __restrict__ cap_l,
    float* __restrict__ pooled,              // [128,128] fp32
    int vb, float* wmax)                     // wmax LDS >= 2*16*W
{
  const int i0  = (vb >> 3) * 2;
  const int cg0 = (vb & 7) * 16;
  const int tid = threadIdx.x;
  const int wv = tid >> 6, lane = tid & 63;
  const int quad = lane >> 4, n16 = lane & 15;
  const int ol0 = obj_l[i0], ol1 = obj_l[i0 + 1];

  bf16x8 af[2][MT][4];
#pragma unroll
  for (int im = 0; im < 2; ++im) {
    const unsigned short* Ab =
        A + (((size_t)(i0 + im) * (MT * 16) + n16) << 7) + quad * 8;
#pragma unroll
    for (int t = 0; t < MT; ++t)
#pragma unroll
      for (int s = 0; s < 4; ++s)
        af[im][t][s] = load_frag(Ab + ((t * 16) << 7) + s * 32);
  }

  const unsigned short* Bbase = Bw + (((size_t)cg0 * W + n16) << 7) + quad * 8;

  for (int nt = wv; nt < W; nt += 4) {     // 16*W/16 = W tiles, exact
    const unsigned short* bp = Bbase + ((nt * 16) << 7);
    bf16x8 bfrag[4];
#pragma unroll
    for (int s = 0; s < 4; ++s) bfrag[s] = load_frag(bp + s * 32);

    f32x4 acc[2][MT];
#pragma unroll
    for (int im = 0; im < 2; ++im)
#pragma unroll
      for (int t = 0; t < MT; ++t) { f32x4 z = {0.f,0.f,0.f,0.f}; acc[im][t] = z; }
#pragma unroll
    for (int s = 0; s < 4; ++s)
#pragma unroll
      for (int im = 0; im < 2; ++im)
#pragma unroll
        for (int t = 0; t < MT; ++t)
          acc[im][t] = __builtin_amdgcn_mfma_f32_16x16x32_bf16(
              af[im][t][s], bfrag[s], acc[im][t], 0, 0, 0);

#pragma unroll
    for (int im = 0; im < 2; ++im) {
      const int ol = im ? ol1 : ol0;
      float m = -3.0e38f;
#pragma unroll
      for (int t = 0; t < MT; ++t)
#pragma unroll
        for (int r = 0; r < 4; ++r) {
          int o = t * 16 + quad * 4 + r;
          if (o < ol) m = fmaxf(m, acc[im][t][r]);
        }
      m = fmaxf(m, __shfl_xor(m, 16));
      m = fmaxf(m, __shfl_xor(m, 32));
      if (quad == 0) wmax[im * (16 * W) + nt * 16 + n16] = m;
    }
  }
  __syncthreads();

  if (tid < 32) {
    const int im = tid >> 4, c = tid & 15;
    const float* wp = wmax + im * (16 * W) + c * W;
    float ssum = 0.f;
    for (int w = 0; w < W; ++w) ssum += wp[w];
    const int cc = cg0 + c;
    pooled[((i0 + im) << 7) + cc] = ssum / (float)cap_l[cc];
  }
}

// ---------------------------------------------------------------------------
// Inline hinge loss, 256 threads, run by the LAST block (R4-verified).
// Coalesced: thread (half,j) scans 64 rows with j contiguous. Row max via
// wave shfl + LDS atomicMax on float bits (hinges >= 0). Col max in regs.
// ---------------------------------------------------------------------------
__device__ __forceinline__ void loss_inline(
    const float* __restrict__ p1, const float* __restrict__ p2,
    float* __restrict__ out, float* smem)
{
  float* diag    = smem;                // [128]
  int*   rowmaxi = (int*)(smem + 128);  // [128]
  float* colmax  = smem + 256;          // [2][128]
  float* wred    = smem + 512;          // [4]
  const int tid = threadIdx.x;
  const int j = tid & 127, half = tid >> 7;
  if (half == 0) {
    diag[j] = p1[j * 129] + p2[j * 129];
    rowmaxi[j] = 0;                     // float bits of 0.0f
  }
  __syncthreads();

  float colp = 0.f;
  for (int rr = 0; rr < 64; ++rr) {
    const int row = half * 64 + rr;
    const float sc = p1[row * 128 + j] + p2[row * 128 + j];
    float rh = (j == row) ? 0.f : fmaxf(0.2f + sc - diag[row], 0.f);
    const float ch = (j == row) ? 0.f : fmaxf(0.2f + sc - diag[j], 0.f);
    colp = fmaxf(colp, ch);
#pragma unroll
    for (int o = 32; o; o >>= 1) rh = fmaxf(rh, __shfl_xor(rh, o));
    if ((tid & 63) == 0) atomicMax(&rowmaxi[row], __float_as_int(rh));
  }
  colmax[half * 128 + j] = colp;
  __syncthreads();

  float v;
  if (tid < 128) v = __int_as_float(rowmaxi[tid]);
  else           v = fmaxf(colmax[tid - 128], colmax[128 + (tid - 128)]);
#pragma unroll
  for (int o = 32; o; o >>= 1) v += __shfl_xor(v, o);
  if ((tid & 63) == 0) wred[tid >> 6] = v;
  __syncthreads();
  if (tid == 0) out[0] = wred[0] + wred[1] + wred[2] + wred[3];
}

// ---------------------------------------------------------------------------
// Fused t2i (both terms) + last-block loss. launch_bounds(256,2): VGPR cap
// 256 -> forbids the 104-VGPR spill tier that caused R4's 125 us stall
// (af[2][3][4]=96 VGPR must stay register-resident).
// ---------------------------------------------------------------------------
__global__ __launch_bounds__(256, 2) void t2i_loss(
    const unsigned short* __restrict__ imb, const unsigned short* __restrict__ sb,
    const unsigned short* __restrict__ pb,  const unsigned short* __restrict__ cb,
    const int* __restrict__ im_l, const int* __restrict__ s_l,
    const int* __restrict__ pred_l, const int* __restrict__ crl,
    float* __restrict__ p1, float* __restrict__ p2,
    unsigned int* __restrict__ counter, float* __restrict__ out)
{
  __shared__ float smem[2 * 16 * 50];
  __shared__ int lastFlag;
  const int b = blockIdx.x;

  if (b < 512) t2i_im2<3, 50>(imb, sb, im_l, s_l, p1, b, smem);
  else         t2i_im2<2, 30>(pb, cb, pred_l, crl, p2, b - 512, smem);

  __syncthreads();                  // drain pooled stores (vmcnt(0) at barrier)
  if (threadIdx.x == 0) {
    __threadfence();                // agent-scope release
    lastFlag = (atomicAdd(counter, 1u) == 1023u) ? 1 : 0;
  }
  __syncthreads();
  if (lastFlag) {
    __threadfence();                // acquire
    loss_inline(p1, p2, out, smem);
  }
}

// ---------------------------------------------------------------------------
extern "C" void kernel_launch(void* const* d_in, const int* in_sizes, int n_in,
                              void* d_out, int out_size, void* d_ws, size_t ws_size,
                              hipStream_t stream)
{
  const float* im     = (const float*)d_in[0];
  const int*   im_l   = (const int*)  d_in[1];
  const float* s32    = (const float*)d_in[2];
  const int*   s_l    = (const int*)  d_in[3];
  const float* pred   = (const float*)d_in[4];
  const int*   pred_l = (const int*)  d_in[5];
  // d_in[6], d_in[7] unused by the reference.
  const float* crp    = (const float*)d_in[8];
  const int*   crl    = (const int*)  d_in[9];

  char* ws = (char*)d_ws;
  const size_t off_imb = 0;
  const size_t off_sb  = off_imb + (size_t)128 * 48 * 128 * 2;
  const size_t off_pb  = off_sb  + (size_t)128 * 50 * 128 * 2;
  const size_t off_cb  = off_pb  + (size_t)128 * 32 * 128 * 2;
  const size_t off_p1  = off_cb  + (size_t)128 * 30 * 128 * 2;
  const size_t off_p2  = off_p1  + (size_t)128 * 128 * 4;
  const size_t off_ctr = off_p2  + (size_t)128 * 128 * 4;

  unsigned short* imb = (unsigned short*)(ws + off_imb);
  unsigned short* sb  = (unsigned short*)(ws + off_sb);
  unsigned short* pb  = (unsigned short*)(ws + off_pb);
  unsigned short* cb  = (unsigned short*)(ws + off_cb);
  float* p1 = (float*)(ws + off_p1);
  float* p2 = (float*)(ws + off_p2);
  unsigned int* counter = (unsigned int*)(ws + off_ctr);

  hipLaunchKernelGGL(convert_all, dim3(2560), dim3(256), 0, stream,
                     im, s32, pred, crp, imb, sb, pb, cb, counter);
  hipLaunchKernelGGL(t2i_loss, dim3(1024), dim3(256), 0, stream,
                     imb, sb, pb, cb, im_l, s_l, pred_l, crl,
                     p1, p2, counter, (float*)d_out);
}